// Round 6
// baseline (1788.130 us; speedup 1.0000x reference)
//
#include <hip/hip_runtime.h>

// GraphVAE forward, Agg = D^-1/2 (A+I) D^-1/2.
// Edges are coarse-bucketed by dst (256 nodes/bucket); aggregation accumulates
// a 64KB bucket slab in LDS via ds_add_f32 — no per-node sort, no f32 global
// atomics, and the edge scatter writes contiguous runs (kills the 105MB
// write-allocate traffic the per-node CSR scatter showed in rocprof).
// All agg inputs are pre-scaled rows Hs[r] = dinv[r]*H[r], so
//   agg[i] = dinv[i] * ( sum_{e:dst=i} Hs[src_e] + Hs[i] ).

#define NBNODES 256            // nodes per bucket
#define NBUCKETS 391           // ceil(100000/256)
#define EPB 16384              // edges per scatter block
#define NBLK 98                // ceil(1600000/16384)

static __host__ __device__ inline size_t ws_align(size_t x) { return (x + 255) & ~size_t(255); }

// ---------------- S1: per-block bucket histogram + global degree ----------------
__global__ __launch_bounds__(512) void k_hist(const int* __restrict__ dst, int E,
                                              int* __restrict__ hist_g, int* __restrict__ deg) {
    __shared__ int hist[NBUCKETS];
    int t = threadIdx.x;
    if (t < NBUCKETS) hist[t] = 0;
    __syncthreads();
    int base = blockIdx.x * EPB;
    for (int i = t; i < EPB; i += 512) {
        int e = base + i;
        if (e < E) {
            int d = dst[e];
            atomicAdd(&hist[d >> 8], 1);
            atomicAdd(&deg[d], 1);
        }
    }
    __syncthreads();
    if (t < NBUCKETS) hist_g[t * NBLK + blockIdx.x] = hist[t];
}

__global__ void k_dinv(const int* __restrict__ deg, int N, float* __restrict__ dinv) {
    int i = blockIdx.x * blockDim.x + threadIdx.x;
    if (i < N) dinv[i] = rsqrtf((float)(deg[i] + 1));  // +1 self-loop
}

// ---------------- S2: scan hist -> per-(bucket,block) bases + bucket starts ----------------
__global__ __launch_bounds__(512) void k_scan(int* __restrict__ hist_g, int E,
                                              int* __restrict__ bstart) {
    __shared__ int s[512];
    int t = threadIdx.x;
    int total = 0;
    if (t < NBUCKETS) {
        int* row = hist_g + t * NBLK;
        for (int k = 0; k < NBLK; k++) {
            int c = row[k];
            row[k] = total;   // within-bucket exclusive prefix
            total += c;
        }
    }
    s[t] = total;
    __syncthreads();
    // Hillis-Steele inclusive scan over 512
    for (int off = 1; off < 512; off <<= 1) {
        int x = 0;
        if (t >= off) x = s[t - off];
        __syncthreads();
        s[t] += x;
        __syncthreads();
    }
    int start = s[t] - total;  // exclusive
    if (t < NBUCKETS) {
        bstart[t] = start;
        int* row = hist_g + t * NBLK;
        for (int k = 0; k < NBLK; k++) row[k] += start;
    }
    if (t == 0) bstart[NBUCKETS] = E;
}

// ---------------- S3: bucketed scatter, packed (dl<<17)|src ----------------
__global__ __launch_bounds__(512) void k_scatter(const int* __restrict__ src,
                                                 const int* __restrict__ dst, int E,
                                                 const int* __restrict__ hist_g,
                                                 int* __restrict__ ebuf) {
    __shared__ int cur[NBUCKETS];
    int t = threadIdx.x;
    if (t < NBUCKETS) cur[t] = hist_g[t * NBLK + blockIdx.x];
    __syncthreads();
    int base = blockIdx.x * EPB;
    for (int i = t; i < EPB; i += 512) {
        int e = base + i;
        if (e < E) {
            int d = dst[e];
            int sv = src[e];
            int slot = atomicAdd(&cur[d >> 8], 1);
            ebuf[slot] = ((d & 255) << 17) | sv;
        }
    }
}

// ---------------- GEMM: C[N,64] = dinv[r] * (X[N,128] @ W[128,64])[r] ----------------
__global__ __launch_bounds__(256) void k_gemm_in(const float* __restrict__ X,
                                                 const float* __restrict__ W,
                                                 const float* __restrict__ dinv, int N,
                                                 float* __restrict__ C) {
    __shared__ float Ws[128 * 64];
    __shared__ float Xs[16][128];
    int t = threadIdx.x;
    const float4* W4 = (const float4*)W;
    float4* Ws4 = (float4*)Ws;
#pragma unroll
    for (int j = 0; j < 8; j++) Ws4[t + 256 * j] = W4[t + 256 * j];
    int row0 = blockIdx.x * 16;
    const float4* X4 = (const float4*)(X + (size_t)row0 * 128);
    float4* Xs4 = (float4*)&Xs[0][0];
#pragma unroll
    for (int j = 0; j < 2; j++) Xs4[t + 256 * j] = X4[t + 256 * j];
    __syncthreads();
    int r = t >> 4;          // 16 rows
    int c0 = (t & 15) * 4;   // 4 cols per thread
    float a0 = 0.f, a1 = 0.f, a2 = 0.f, a3 = 0.f;
#pragma unroll 4
    for (int k = 0; k < 128; k++) {
        float xv = Xs[r][k];
        float4 w = *(const float4*)&Ws[k * 64 + c0];
        a0 += xv * w.x; a1 += xv * w.y; a2 += xv * w.z; a3 += xv * w.w;
    }
    float dv = dinv[row0 + r];
    float4 out = {a0 * dv, a1 * dv, a2 * dv, a3 * dv};
    *(float4*)(C + (size_t)(row0 + r) * 64 + c0) = out;
}

// ---------------- bucketed aggregation with LDS accumulation ----------------
// FIRST: out = dinv * relu(dinv*sum + b)  (pre-scaled for next agg pass)
// else : out = dinv * sum
template <bool FIRST>
__global__ __launch_bounds__(512) void k_aggb(const float* __restrict__ Hs,
                                              const float* __restrict__ dinv,
                                              const int* __restrict__ bstart,
                                              const int* __restrict__ ebuf,
                                              const float* __restrict__ bias, int N,
                                              float* __restrict__ out) {
    __shared__ float acc[NBNODES * 64];  // 64 KB
    int b = blockIdx.x;
    int nb0 = b << 8;
    int nn = min(NBNODES, N - nb0);
    int t = threadIdx.x;
    // init with self-loop rows (Hs already dinv-scaled)
    float4* a4 = (float4*)acc;
    const float4* H4 = (const float4*)(Hs + (size_t)nb0 * 64);
    for (int i = t; i < nn * 16; i += 512) a4[i] = H4[i];
    __syncthreads();
    int beg = bstart[b], end = bstart[b + 1];
    int cnt = end - beg;
    int wave = t >> 6, lane = t & 63;
    int chunk = (cnt + 7) >> 3;
    int j0 = beg + wave * chunk;
    int j1 = min(j0 + chunk, end);
    int j = j0;
    for (; j + 8 <= j1; j += 8) {
        int e0 = __builtin_amdgcn_readfirstlane(ebuf[j + 0]);
        int e1 = __builtin_amdgcn_readfirstlane(ebuf[j + 1]);
        int e2 = __builtin_amdgcn_readfirstlane(ebuf[j + 2]);
        int e3 = __builtin_amdgcn_readfirstlane(ebuf[j + 3]);
        int e4 = __builtin_amdgcn_readfirstlane(ebuf[j + 4]);
        int e5 = __builtin_amdgcn_readfirstlane(ebuf[j + 5]);
        int e6 = __builtin_amdgcn_readfirstlane(ebuf[j + 6]);
        int e7 = __builtin_amdgcn_readfirstlane(ebuf[j + 7]);
        float v0 = Hs[(size_t)(e0 & 0x1FFFF) * 64 + lane];
        float v1 = Hs[(size_t)(e1 & 0x1FFFF) * 64 + lane];
        float v2 = Hs[(size_t)(e2 & 0x1FFFF) * 64 + lane];
        float v3 = Hs[(size_t)(e3 & 0x1FFFF) * 64 + lane];
        float v4 = Hs[(size_t)(e4 & 0x1FFFF) * 64 + lane];
        float v5 = Hs[(size_t)(e5 & 0x1FFFF) * 64 + lane];
        float v6 = Hs[(size_t)(e6 & 0x1FFFF) * 64 + lane];
        float v7 = Hs[(size_t)(e7 & 0x1FFFF) * 64 + lane];
        atomicAdd(&acc[((unsigned)e0 >> 17) * 64 + lane], v0);
        atomicAdd(&acc[((unsigned)e1 >> 17) * 64 + lane], v1);
        atomicAdd(&acc[((unsigned)e2 >> 17) * 64 + lane], v2);
        atomicAdd(&acc[((unsigned)e3 >> 17) * 64 + lane], v3);
        atomicAdd(&acc[((unsigned)e4 >> 17) * 64 + lane], v4);
        atomicAdd(&acc[((unsigned)e5 >> 17) * 64 + lane], v5);
        atomicAdd(&acc[((unsigned)e6 >> 17) * 64 + lane], v6);
        atomicAdd(&acc[((unsigned)e7 >> 17) * 64 + lane], v7);
    }
    for (; j < j1; j++) {
        int e0 = __builtin_amdgcn_readfirstlane(ebuf[j]);
        float v0 = Hs[(size_t)(e0 & 0x1FFFF) * 64 + lane];
        atomicAdd(&acc[((unsigned)e0 >> 17) * 64 + lane], v0);
    }
    __syncthreads();
    // flush with dinv scale (+bias/relu)
    float4* o4 = (float4*)(out + (size_t)nb0 * 64);
    for (int i = t; i < nn * 16; i += 512) {
        int row = i >> 4;
        float dv = dinv[nb0 + row];
        float4 v = a4[i];
        if (FIRST) {
            int q = i & 15;
            float4 bb = ((const float4*)bias)[q];
            v.x = fmaxf(dv * v.x + bb.x, 0.f) * dv;
            v.y = fmaxf(dv * v.y + bb.y, 0.f) * dv;
            v.z = fmaxf(dv * v.z + bb.z, 0.f) * dv;
            v.w = fmaxf(dv * v.w + bb.w, 0.f) * dv;
        } else {
            v.x *= dv; v.y *= dv; v.z *= dv; v.w *= dv;
        }
        o4[i] = v;
    }
}

// ---------------- Fused mu/logvar/z ----------------
__global__ __launch_bounds__(256) void k_muvz(const float* __restrict__ AGG,
                                              const float* __restrict__ Wmu,
                                              const float* __restrict__ bmu,
                                              const float* __restrict__ Wlv,
                                              const float* __restrict__ blv,
                                              const float* __restrict__ EPS, int N,
                                              float* __restrict__ mu_out,
                                              float* __restrict__ lv_out,
                                              float* __restrict__ z_out) {
    __shared__ float Wm[64 * 64];
    __shared__ float Wl[64 * 64];
    __shared__ float As[16][64];
    int t = threadIdx.x;
#pragma unroll
    for (int j = 0; j < 4; j++) {
        ((float4*)Wm)[t + 256 * j] = ((const float4*)Wmu)[t + 256 * j];
        ((float4*)Wl)[t + 256 * j] = ((const float4*)Wlv)[t + 256 * j];
    }
    int row0 = blockIdx.x * 16;
    ((float4*)&As[0][0])[t] = ((const float4*)(AGG + (size_t)row0 * 64))[t];
    __syncthreads();
    int r = t >> 4;
    int c0 = (t & 15) * 4;
    float m0 = 0.f, m1 = 0.f, m2 = 0.f, m3 = 0.f;
    float l0 = 0.f, l1 = 0.f, l2 = 0.f, l3 = 0.f;
#pragma unroll 4
    for (int k = 0; k < 64; k++) {
        float a = As[r][k];
        float4 wm = *(const float4*)&Wm[k * 64 + c0];
        float4 wl = *(const float4*)&Wl[k * 64 + c0];
        m0 += a * wm.x; m1 += a * wm.y; m2 += a * wm.z; m3 += a * wm.w;
        l0 += a * wl.x; l1 += a * wl.y; l2 += a * wl.z; l3 += a * wl.w;
    }
    size_t base = (size_t)(row0 + r) * 64 + c0;
    float4 bm = *(const float4*)&bmu[c0];
    float4 bl = *(const float4*)&blv[c0];
    float4 ep = *(const float4*)&EPS[base];
    m0 += bm.x; m1 += bm.y; m2 += bm.z; m3 += bm.w;
    l0 += bl.x; l1 += bl.y; l2 += bl.z; l3 += bl.w;
    float z0 = m0 + ep.x * expf(l0);
    float z1 = m1 + ep.y * expf(l1);
    float z2 = m2 + ep.z * expf(l2);
    float z3 = m3 + ep.w * expf(l3);
    *(float4*)&mu_out[base] = {m0, m1, m2, m3};
    *(float4*)&lv_out[base] = {l0, l1, l2, l3};
    *(float4*)&z_out[base] = {z0, z1, z2, z3};
}

// ---------------- Decoder: recon = sigmoid(Z[N,64] @ Wdec[64,128] + bdec) ----------------
__global__ __launch_bounds__(256) void k_dec(const float* __restrict__ Z,
                                             const float* __restrict__ Wdec,
                                             const float* __restrict__ bdec, int N,
                                             float* __restrict__ recon) {
    __shared__ float Ws[64 * 128];
    __shared__ float Zs[16][64];
    int t = threadIdx.x;
#pragma unroll
    for (int j = 0; j < 8; j++)
        ((float4*)Ws)[t + 256 * j] = ((const float4*)Wdec)[t + 256 * j];
    int row0 = blockIdx.x * 16;
    ((float4*)&Zs[0][0])[t] = ((const float4*)(Z + (size_t)row0 * 64))[t];
    __syncthreads();
    int r = t >> 4;
    int c0 = (t & 15) * 8;  // 8 cols per thread
    float a[8] = {0.f, 0.f, 0.f, 0.f, 0.f, 0.f, 0.f, 0.f};
#pragma unroll 4
    for (int k = 0; k < 64; k++) {
        float zv = Zs[r][k];
        float4 w0 = *(const float4*)&Ws[k * 128 + c0];
        float4 w1 = *(const float4*)&Ws[k * 128 + c0 + 4];
        a[0] += zv * w0.x; a[1] += zv * w0.y; a[2] += zv * w0.z; a[3] += zv * w0.w;
        a[4] += zv * w1.x; a[5] += zv * w1.y; a[6] += zv * w1.z; a[7] += zv * w1.w;
    }
    size_t base = (size_t)(row0 + r) * 128 + c0;
    float4 b0 = *(const float4*)&bdec[c0];
    float4 b1 = *(const float4*)&bdec[c0 + 4];
    float v0 = a[0] + b0.x, v1 = a[1] + b0.y, v2 = a[2] + b0.z, v3 = a[3] + b0.w;
    float v4 = a[4] + b1.x, v5 = a[5] + b1.y, v6 = a[6] + b1.z, v7 = a[7] + b1.w;
    float4 o0 = {1.f / (1.f + expf(-v0)), 1.f / (1.f + expf(-v1)),
                 1.f / (1.f + expf(-v2)), 1.f / (1.f + expf(-v3))};
    float4 o1 = {1.f / (1.f + expf(-v4)), 1.f / (1.f + expf(-v5)),
                 1.f / (1.f + expf(-v6)), 1.f / (1.f + expf(-v7))};
    *(float4*)&recon[base] = o0;
    *(float4*)&recon[base + 4] = o1;
}

extern "C" void kernel_launch(void* const* d_in, const int* in_sizes, int n_in,
                              void* d_out, int out_size, void* d_ws, size_t ws_size,
                              hipStream_t stream) {
    const float* x = (const float*)d_in[0];
    const int* edge_index = (const int*)d_in[1];
    const float* eps = (const float*)d_in[2];
    const float* W1 = (const float*)d_in[3];
    const float* b1 = (const float*)d_in[4];
    const float* Wmu = (const float*)d_in[5];
    const float* bmu = (const float*)d_in[6];
    const float* Wlv = (const float*)d_in[7];
    const float* blv = (const float*)d_in[8];
    const float* Wdec = (const float*)d_in[9];
    const float* bdec = (const float*)d_in[10];

    int N = in_sizes[0] / 128;
    int E = in_sizes[1] / 2;
    const int* src = edge_index;       // edge_index[0]
    const int* dst = edge_index + E;   // edge_index[1]

    float* recon = (float*)d_out;                      // [N,128]
    float* mu_out = (float*)d_out + (size_t)N * 128;   // [N,64]
    float* lv_out = mu_out + (size_t)N * 64;           // [N,64]

    // workspace layout
    char* p = (char*)d_ws;
    auto alloc = [&](size_t bytes) { char* r = p; p += ws_align(bytes); return r; };
    int* deg = (int*)alloc((size_t)N * 4);
    float* dinv = (float*)alloc((size_t)N * 4);
    int* hist_g = (int*)alloc((size_t)NBUCKETS * NBLK * 4);
    int* bstart = (int*)alloc((size_t)(NBUCKETS + 1) * 4);
    int* ebuf = (int*)alloc((size_t)E * 4);
    float* bufA = (float*)alloc((size_t)N * 64 * 4);  // dinv*(x@W1), then agg(h)
    float* bufB = (float*)alloc((size_t)N * 64 * 4);  // dinv*h, then z

    hipMemsetAsync(deg, 0, (size_t)N * 4, stream);

    k_hist<<<NBLK, 512, 0, stream>>>(dst, E, hist_g, deg);
    k_dinv<<<(N + 255) / 256, 256, 0, stream>>>(deg, N, dinv);
    k_scan<<<1, 512, 0, stream>>>(hist_g, E, bstart);
    k_scatter<<<NBLK, 512, 0, stream>>>(src, dst, E, hist_g, ebuf);

    k_gemm_in<<<N / 16, 256, 0, stream>>>(x, W1, dinv, N, bufA);  // dinv*(x@W1)
    k_aggb<true><<<NBUCKETS, 512, 0, stream>>>(bufA, dinv, bstart, ebuf, b1, N, bufB);     // dinv*h
    k_aggb<false><<<NBUCKETS, 512, 0, stream>>>(bufB, dinv, bstart, ebuf, nullptr, N, bufA); // agg(h)
    k_muvz<<<N / 16, 256, 0, stream>>>(bufA, Wmu, bmu, Wlv, blv, eps, N, mu_out, lv_out, bufB);
    k_dec<<<N / 16, 256, 0, stream>>>(bufB, Wdec, bdec, N, recon);
}

// Round 7
// 568.931 us; speedup vs baseline: 3.1430x; 3.1430x over previous
//
#include <hip/hip_runtime.h>

// GraphVAE forward, Agg = D^-1/2 (A+I) D^-1/2.
// Pipeline: bucket-histogram -> scan -> bucketed scatter (contiguous writes)
// -> per-bucket counting sort to full CSR -> wave-per-node register
// aggregation (100k waves, full occupancy). Lesson from r6 counters: the
// 391-block LDS-slab agg was latency-bound at 25% occupancy (692us); per-node
// waves with 8 gathers in flight is the parallel formulation.
// All agg inputs are pre-scaled rows Hs[r] = dinv[r]*H[r], so
//   agg[i] = dinv[i] * ( sum_{e:dst=i} Hs[src_e] + Hs[i] ).

#define NBNODES 256            // nodes per bucket
#define NBUCKETS 391           // ceil(100000/256)
#define EPB 16384              // edges per scatter block
#define NBLK 98                // ceil(1600000/16384)

static __host__ __device__ inline size_t ws_align(size_t x) { return (x + 255) & ~size_t(255); }

// ---------------- S1: per-block bucket histogram + global degree ----------------
__global__ __launch_bounds__(512) void k_hist(const int* __restrict__ dst, int E,
                                              int* __restrict__ hist_g, int* __restrict__ deg) {
    __shared__ int hist[NBUCKETS];
    int t = threadIdx.x;
    if (t < NBUCKETS) hist[t] = 0;
    __syncthreads();
    int base = blockIdx.x * EPB;
    for (int i = t; i < EPB; i += 512) {
        int e = base + i;
        if (e < E) {
            int d = dst[e];
            atomicAdd(&hist[d >> 8], 1);
            atomicAdd(&deg[d], 1);
        }
    }
    __syncthreads();
    if (t < NBUCKETS) hist_g[t * NBLK + blockIdx.x] = hist[t];
}

__global__ void k_dinv(const int* __restrict__ deg, int N, float* __restrict__ dinv) {
    int i = blockIdx.x * blockDim.x + threadIdx.x;
    if (i < N) dinv[i] = rsqrtf((float)(deg[i] + 1));  // +1 self-loop
}

// ---------------- S2: scan hist -> per-(bucket,block) bases + bucket starts ----------------
__global__ __launch_bounds__(512) void k_scan(int* __restrict__ hist_g, int E, int N,
                                              int* __restrict__ bstart, int* __restrict__ offs) {
    __shared__ int s[512];
    int t = threadIdx.x;
    int total = 0;
    if (t < NBUCKETS) {
        int* row = hist_g + t * NBLK;
        for (int k = 0; k < NBLK; k++) {
            int c = row[k];
            row[k] = total;   // within-bucket exclusive prefix
            total += c;
        }
    }
    s[t] = total;
    __syncthreads();
    // Hillis-Steele inclusive scan over 512
    for (int off = 1; off < 512; off <<= 1) {
        int x = 0;
        if (t >= off) x = s[t - off];
        __syncthreads();
        s[t] += x;
        __syncthreads();
    }
    int start = s[t] - total;  // exclusive
    if (t < NBUCKETS) {
        bstart[t] = start;
        int* row = hist_g + t * NBLK;
        for (int k = 0; k < NBLK; k++) row[k] += start;
    }
    if (t == 0) {
        bstart[NBUCKETS] = E;
        offs[N] = E;
    }
}

// ---------------- S3: bucketed scatter, packed (dl<<17)|src ----------------
__global__ __launch_bounds__(512) void k_scatter(const int* __restrict__ src,
                                                 const int* __restrict__ dst, int E,
                                                 const int* __restrict__ hist_g,
                                                 int* __restrict__ ebuf) {
    __shared__ int cur[NBUCKETS];
    int t = threadIdx.x;
    if (t < NBUCKETS) cur[t] = hist_g[t * NBLK + blockIdx.x];
    __syncthreads();
    int base = blockIdx.x * EPB;
    for (int i = t; i < EPB; i += 512) {
        int e = base + i;
        if (e < E) {
            int d = dst[e];
            int sv = src[e];
            int slot = atomicAdd(&cur[d >> 8], 1);
            ebuf[slot] = ((d & 255) << 17) | sv;
        }
    }
}

// ---------------- S4: per-bucket counting sort -> full CSR + node offsets ----------------
__global__ __launch_bounds__(256) void k_sortb(const int* __restrict__ ebuf,
                                               const int* __restrict__ bstart, int N,
                                               int* __restrict__ csr, int* __restrict__ offs) {
    __shared__ int cnt[256];
    __shared__ int sc[256];
    int b = blockIdx.x;
    int t = threadIdx.x;
    int beg = bstart[b], end = bstart[b + 1];
    cnt[t] = 0;
    __syncthreads();
    for (int i = beg + t; i < end; i += 256)
        atomicAdd(&cnt[(unsigned)ebuf[i] >> 17], 1);
    __syncthreads();
    int my = cnt[t];
    sc[t] = my;
    __syncthreads();
    for (int off = 1; off < 256; off <<= 1) {
        int x = 0;
        if (t >= off) x = sc[t - off];
        __syncthreads();
        sc[t] += x;
        __syncthreads();
    }
    int excl = sc[t] - my;           // exclusive prefix within bucket
    int nb0 = b << 8;
    if (nb0 + t < N) offs[nb0 + t] = beg + excl;
    __syncthreads();
    cnt[t] = beg + excl;             // reuse as cursor
    __syncthreads();
    for (int i = beg + t; i < end; i += 256) {
        int e = ebuf[i];
        int slot = atomicAdd(&cnt[(unsigned)e >> 17], 1);
        csr[slot] = e & 0x1FFFF;
    }
}

// ---------------- GEMM: C[N,64] = dinv[r] * (X[N,128] @ W[128,64])[r] ----------------
__global__ __launch_bounds__(256) void k_gemm_in(const float* __restrict__ X,
                                                 const float* __restrict__ W,
                                                 const float* __restrict__ dinv, int N,
                                                 float* __restrict__ C) {
    __shared__ float Ws[128 * 64];
    __shared__ float Xs[16][128];
    int t = threadIdx.x;
    const float4* W4 = (const float4*)W;
    float4* Ws4 = (float4*)Ws;
#pragma unroll
    for (int j = 0; j < 8; j++) Ws4[t + 256 * j] = W4[t + 256 * j];
    int row0 = blockIdx.x * 16;
    const float4* X4 = (const float4*)(X + (size_t)row0 * 128);
    float4* Xs4 = (float4*)&Xs[0][0];
#pragma unroll
    for (int j = 0; j < 2; j++) Xs4[t + 256 * j] = X4[t + 256 * j];
    __syncthreads();
    int r = t >> 4;          // 16 rows
    int c0 = (t & 15) * 4;   // 4 cols per thread
    float a0 = 0.f, a1 = 0.f, a2 = 0.f, a3 = 0.f;
#pragma unroll 4
    for (int k = 0; k < 128; k++) {
        float xv = Xs[r][k];
        float4 w = *(const float4*)&Ws[k * 64 + c0];
        a0 += xv * w.x; a1 += xv * w.y; a2 += xv * w.z; a3 += xv * w.w;
    }
    float dv = dinv[row0 + r];
    float4 out = {a0 * dv, a1 * dv, a2 * dv, a3 * dv};
    *(float4*)(C + (size_t)(row0 + r) * 64 + c0) = out;
}

// ---------------- wave-per-node aggregation over pre-scaled rows ----------------
// FIRST: out = dinv * relu(dinv*sum + b)   (pre-scaled for next agg pass)
// else : out = dinv * sum
template <bool FIRST>
__global__ __launch_bounds__(256) void k_agg(const float* __restrict__ Hs,
                                             const float* __restrict__ dinv,
                                             const int* __restrict__ offs,
                                             const int* __restrict__ csr,
                                             const float* __restrict__ bias, int N,
                                             float* __restrict__ out) {
    int node = blockIdx.x * 4 + (threadIdx.x >> 6);  // one wave per node
    int lane = threadIdx.x & 63;                     // lane = feature
    if (node >= N) return;
    float dv = dinv[node];
    int beg = offs[node], end = offs[node + 1];
    int nu = __builtin_amdgcn_readfirstlane(node);
    float acc0 = Hs[(size_t)nu * 64 + lane];  // self-loop row (pre-scaled)
    float acc1 = 0.f, acc2 = 0.f, acc3 = 0.f;
    int j = beg;
    for (; j + 8 <= end; j += 8) {
        int s0 = __builtin_amdgcn_readfirstlane(csr[j + 0]);
        int s1 = __builtin_amdgcn_readfirstlane(csr[j + 1]);
        int s2 = __builtin_amdgcn_readfirstlane(csr[j + 2]);
        int s3 = __builtin_amdgcn_readfirstlane(csr[j + 3]);
        int s4 = __builtin_amdgcn_readfirstlane(csr[j + 4]);
        int s5 = __builtin_amdgcn_readfirstlane(csr[j + 5]);
        int s6 = __builtin_amdgcn_readfirstlane(csr[j + 6]);
        int s7 = __builtin_amdgcn_readfirstlane(csr[j + 7]);
        float h0 = Hs[(size_t)s0 * 64 + lane];
        float h1 = Hs[(size_t)s1 * 64 + lane];
        float h2 = Hs[(size_t)s2 * 64 + lane];
        float h3 = Hs[(size_t)s3 * 64 + lane];
        float h4 = Hs[(size_t)s4 * 64 + lane];
        float h5 = Hs[(size_t)s5 * 64 + lane];
        float h6 = Hs[(size_t)s6 * 64 + lane];
        float h7 = Hs[(size_t)s7 * 64 + lane];
        acc0 += h0 + h1;
        acc1 += h2 + h3;
        acc2 += h4 + h5;
        acc3 += h6 + h7;
    }
    for (; j < end; j++) {
        int s = __builtin_amdgcn_readfirstlane(csr[j]);
        acc0 += Hs[(size_t)s * 64 + lane];
    }
    float acc = (acc0 + acc1) + (acc2 + acc3);
    float v;
    if (FIRST) {
        v = dv * acc + bias[lane];
        v = fmaxf(v, 0.f) * dv;  // pre-scale for second agg pass
    } else {
        v = dv * acc;
    }
    out[(size_t)node * 64 + lane] = v;
}

// ---------------- Fused mu/logvar/z ----------------
__global__ __launch_bounds__(256) void k_muvz(const float* __restrict__ AGG,
                                              const float* __restrict__ Wmu,
                                              const float* __restrict__ bmu,
                                              const float* __restrict__ Wlv,
                                              const float* __restrict__ blv,
                                              const float* __restrict__ EPS, int N,
                                              float* __restrict__ mu_out,
                                              float* __restrict__ lv_out,
                                              float* __restrict__ z_out) {
    __shared__ float Wm[64 * 64];
    __shared__ float Wl[64 * 64];
    __shared__ float As[16][64];
    int t = threadIdx.x;
#pragma unroll
    for (int j = 0; j < 4; j++) {
        ((float4*)Wm)[t + 256 * j] = ((const float4*)Wmu)[t + 256 * j];
        ((float4*)Wl)[t + 256 * j] = ((const float4*)Wlv)[t + 256 * j];
    }
    int row0 = blockIdx.x * 16;
    ((float4*)&As[0][0])[t] = ((const float4*)(AGG + (size_t)row0 * 64))[t];
    __syncthreads();
    int r = t >> 4;
    int c0 = (t & 15) * 4;
    float m0 = 0.f, m1 = 0.f, m2 = 0.f, m3 = 0.f;
    float l0 = 0.f, l1 = 0.f, l2 = 0.f, l3 = 0.f;
#pragma unroll 4
    for (int k = 0; k < 64; k++) {
        float a = As[r][k];
        float4 wm = *(const float4*)&Wm[k * 64 + c0];
        float4 wl = *(const float4*)&Wl[k * 64 + c0];
        m0 += a * wm.x; m1 += a * wm.y; m2 += a * wm.z; m3 += a * wm.w;
        l0 += a * wl.x; l1 += a * wl.y; l2 += a * wl.z; l3 += a * wl.w;
    }
    size_t base = (size_t)(row0 + r) * 64 + c0;
    float4 bm = *(const float4*)&bmu[c0];
    float4 bl = *(const float4*)&blv[c0];
    float4 ep = *(const float4*)&EPS[base];
    m0 += bm.x; m1 += bm.y; m2 += bm.z; m3 += bm.w;
    l0 += bl.x; l1 += bl.y; l2 += bl.z; l3 += bl.w;
    float z0 = m0 + ep.x * expf(l0);
    float z1 = m1 + ep.y * expf(l1);
    float z2 = m2 + ep.z * expf(l2);
    float z3 = m3 + ep.w * expf(l3);
    *(float4*)&mu_out[base] = {m0, m1, m2, m3};
    *(float4*)&lv_out[base] = {l0, l1, l2, l3};
    *(float4*)&z_out[base] = {z0, z1, z2, z3};
}

// ---------------- Decoder: recon = sigmoid(Z[N,64] @ Wdec[64,128] + bdec) ----------------
__global__ __launch_bounds__(256) void k_dec(const float* __restrict__ Z,
                                             const float* __restrict__ Wdec,
                                             const float* __restrict__ bdec, int N,
                                             float* __restrict__ recon) {
    __shared__ float Ws[64 * 128];
    __shared__ float Zs[16][64];
    int t = threadIdx.x;
#pragma unroll
    for (int j = 0; j < 8; j++)
        ((float4*)Ws)[t + 256 * j] = ((const float4*)Wdec)[t + 256 * j];
    int row0 = blockIdx.x * 16;
    ((float4*)&Zs[0][0])[t] = ((const float4*)(Z + (size_t)row0 * 64))[t];
    __syncthreads();
    int r = t >> 4;
    int c0 = (t & 15) * 8;  // 8 cols per thread
    float a[8] = {0.f, 0.f, 0.f, 0.f, 0.f, 0.f, 0.f, 0.f};
#pragma unroll 4
    for (int k = 0; k < 64; k++) {
        float zv = Zs[r][k];
        float4 w0 = *(const float4*)&Ws[k * 128 + c0];
        float4 w1 = *(const float4*)&Ws[k * 128 + c0 + 4];
        a[0] += zv * w0.x; a[1] += zv * w0.y; a[2] += zv * w0.z; a[3] += zv * w0.w;
        a[4] += zv * w1.x; a[5] += zv * w1.y; a[6] += zv * w1.z; a[7] += zv * w1.w;
    }
    size_t base = (size_t)(row0 + r) * 128 + c0;
    float4 b0 = *(const float4*)&bdec[c0];
    float4 b1 = *(const float4*)&bdec[c0 + 4];
    float v0 = a[0] + b0.x, v1 = a[1] + b0.y, v2 = a[2] + b0.z, v3 = a[3] + b0.w;
    float v4 = a[4] + b1.x, v5 = a[5] + b1.y, v6 = a[6] + b1.z, v7 = a[7] + b1.w;
    float4 o0 = {1.f / (1.f + expf(-v0)), 1.f / (1.f + expf(-v1)),
                 1.f / (1.f + expf(-v2)), 1.f / (1.f + expf(-v3))};
    float4 o1 = {1.f / (1.f + expf(-v4)), 1.f / (1.f + expf(-v5)),
                 1.f / (1.f + expf(-v6)), 1.f / (1.f + expf(-v7))};
    *(float4*)&recon[base] = o0;
    *(float4*)&recon[base + 4] = o1;
}

extern "C" void kernel_launch(void* const* d_in, const int* in_sizes, int n_in,
                              void* d_out, int out_size, void* d_ws, size_t ws_size,
                              hipStream_t stream) {
    const float* x = (const float*)d_in[0];
    const int* edge_index = (const int*)d_in[1];
    const float* eps = (const float*)d_in[2];
    const float* W1 = (const float*)d_in[3];
    const float* b1 = (const float*)d_in[4];
    const float* Wmu = (const float*)d_in[5];
    const float* bmu = (const float*)d_in[6];
    const float* Wlv = (const float*)d_in[7];
    const float* blv = (const float*)d_in[8];
    const float* Wdec = (const float*)d_in[9];
    const float* bdec = (const float*)d_in[10];

    int N = in_sizes[0] / 128;
    int E = in_sizes[1] / 2;
    const int* src = edge_index;       // edge_index[0]
    const int* dst = edge_index + E;   // edge_index[1]

    float* recon = (float*)d_out;                      // [N,128]
    float* mu_out = (float*)d_out + (size_t)N * 128;   // [N,64]
    float* lv_out = mu_out + (size_t)N * 64;           // [N,64]

    // workspace layout
    char* p = (char*)d_ws;
    auto alloc = [&](size_t bytes) { char* r = p; p += ws_align(bytes); return r; };
    int* deg = (int*)alloc((size_t)N * 4);
    float* dinv = (float*)alloc((size_t)N * 4);
    int* hist_g = (int*)alloc((size_t)NBUCKETS * NBLK * 4);
    int* bstart = (int*)alloc((size_t)(NBUCKETS + 1) * 4);
    int* ebuf = (int*)alloc((size_t)E * 4);
    int* csr = (int*)alloc((size_t)E * 4);
    int* offs = (int*)alloc((size_t)(N + 1) * 4);
    float* bufA = (float*)alloc((size_t)N * 64 * 4);  // dinv*(x@W1), then agg(h)
    float* bufB = (float*)alloc((size_t)N * 64 * 4);  // dinv*h, then z

    hipMemsetAsync(deg, 0, (size_t)N * 4, stream);

    k_hist<<<NBLK, 512, 0, stream>>>(dst, E, hist_g, deg);
    k_dinv<<<(N + 255) / 256, 256, 0, stream>>>(deg, N, dinv);
    k_scan<<<1, 512, 0, stream>>>(hist_g, E, N, bstart, offs);
    k_scatter<<<NBLK, 512, 0, stream>>>(src, dst, E, hist_g, ebuf);
    k_sortb<<<NBUCKETS, 256, 0, stream>>>(ebuf, bstart, N, csr, offs);

    k_gemm_in<<<N / 16, 256, 0, stream>>>(x, W1, dinv, N, bufA);  // dinv*(x@W1)
    k_agg<true><<<(N + 3) / 4, 256, 0, stream>>>(bufA, dinv, offs, csr, b1, N, bufB);      // dinv*h
    k_agg<false><<<(N + 3) / 4, 256, 0, stream>>>(bufB, dinv, offs, csr, nullptr, N, bufA); // agg(h)
    k_muvz<<<N / 16, 256, 0, stream>>>(bufA, Wmu, bmu, Wlv, blv, eps, N, mu_out, lv_out, bufB);
    k_dec<<<N / 16, 256, 0, stream>>>(bufB, Wdec, bdec, N, recon);
}